// Round 9
// baseline (858.566 us; speedup 1.0000x reference)
//
#include <hip/hip_runtime.h>
#include <math.h>

#define T_SEQ 1024
#define TA_SEQ 1024
#define BATCH 8
#define CH 1024
#define NH 16
#define HD 64
#define MH 4096

typedef unsigned short u16;
typedef unsigned short u16x4 __attribute__((ext_vector_type(4)));
typedef unsigned short u16x8 __attribute__((ext_vector_type(8)));
typedef __bf16 bf16x8 __attribute__((ext_vector_type(8)));
typedef float f32x4 __attribute__((ext_vector_type(4)));

__device__ __forceinline__ u16 f2bf(float f) {
  unsigned int u = __builtin_bit_cast(unsigned int, f);
  u += 0x7FFFu + ((u >> 16) & 1u);   // RNE
  return (u16)(u >> 16);
}
__device__ __forceinline__ u16 f2bf_trunc(float f) {   // cheap cvt for P (p >= 0)
  return (u16)(__builtin_bit_cast(unsigned int, f) >> 16);
}
__device__ __forceinline__ bf16x8 ldbf8(const u16* p) {
  return __builtin_bit_cast(bf16x8, *reinterpret_cast<const u16x8*>(p));
}
// async global->LDS, 16B per lane (dest must be wave-uniform base + lane*16)
__device__ __forceinline__ void gload_lds16(const u16* g, u16* l) {
  __builtin_amdgcn_global_load_lds(
      (const __attribute__((address_space(1))) unsigned int*)g,
      (__attribute__((address_space(3))) unsigned int*)l, 16, 0, 0);
}

// raw barrier / counted waits (T4: never drain vmcnt(0) in the main loop).
// "memory" clobber pins all C++ memory ops (builtin s_barrier is NOT a fence).
#define ASM_BAR()   asm volatile("s_barrier" ::: "memory")
#define ASM_VM8()   asm volatile("s_waitcnt vmcnt(8)" ::: "memory")
#define ASM_VM6()   asm volatile("s_waitcnt vmcnt(6)" ::: "memory")
#define ASM_VM4()   asm volatile("s_waitcnt vmcnt(4)" ::: "memory")
#define ASM_VM3()   asm volatile("s_waitcnt vmcnt(3)" ::: "memory")
#define ASM_VM0()   asm volatile("s_waitcnt vmcnt(0)" ::: "memory")
#define ASM_LGKM0() asm volatile("s_waitcnt lgkmcnt(0)" ::: "memory")

// ------------- weight transpose-convert: fp32 in[K][N] -> bf16 out[N][K] -------------
__global__ void k_transpose_w(const float* __restrict__ in, u16* __restrict__ out,
                              int K, int N) {
  __shared__ float tile[32][33];
  int n0 = blockIdx.x * 32, k0 = blockIdx.y * 32;
  int tx = threadIdx.x, ty = threadIdx.y;   // block (32,8)
#pragma unroll
  for (int i = 0; i < 4; i++)
    tile[ty + i * 8][tx] = in[(size_t)(k0 + ty + i * 8) * N + n0 + tx];
  __syncthreads();
#pragma unroll
  for (int i = 0; i < 4; i++)
    out[(size_t)(n0 + ty + i * 8) * K + k0 + tx] = f2bf(tile[tx][ty + i * 8]);
}

// batched version for the 8 square (1024x1024) weights: one dispatch, blockIdx.z selects
struct P8f { const float* p[8]; };
struct P8u { u16* p[8]; };
__global__ void k_transpose8(P8f in8, P8u out8) {
  const float* __restrict__ in = in8.p[blockIdx.z];
  u16* __restrict__ out = out8.p[blockIdx.z];
  __shared__ float tile[32][33];
  int n0 = blockIdx.x * 32, k0 = blockIdx.y * 32;
  int tx = threadIdx.x, ty = threadIdx.y;   // block (32,8)
#pragma unroll
  for (int i = 0; i < 4; i++)
    tile[ty + i * 8][tx] = in[(size_t)(k0 + ty + i * 8) * CH + n0 + tx];
  __syncthreads();
#pragma unroll
  for (int i = 0; i < 4; i++)
    out[(size_t)(n0 + ty + i * 8) * CH + k0 + tx] = f2bf(tile[tx][ty + i * 8]);
}

// ------------- adaLN modulation: mod[b][6C] = silu(c[b]) @ w_ada + b_ada -------------
__global__ void k_ada(const float* __restrict__ c, const float* __restrict__ w_ada,
                      const float* __restrict__ b_ada, float* __restrict__ mod) {
  __shared__ float sc[CH];
  int b = blockIdx.y;
  int tid = threadIdx.x;
  for (int i = tid; i < CH; i += 256) {
    float cv = c[b * CH + i];
    sc[i] = cv / (1.0f + expf(-cv));   // silu
  }
  __syncthreads();
  int n = blockIdx.x * 256 + tid;
  float acc = 0.0f;
  for (int k = 0; k < CH; k++) acc += sc[k] * w_ada[(size_t)k * (6 * CH) + n];
  mod[(size_t)b * (6 * CH) + n] = acc + b_ada[n];
}

// ------------- audio [TA][B][C] fp32 -> batch-major [B*TA][C] bf16 -------------
__global__ void k_tbc_to_btc_bf16(const float* __restrict__ in, u16* __restrict__ out) {
  size_t i = (size_t)blockIdx.x * 256 + threadIdx.x;
  int c = (int)(i & (CH - 1));
  size_t tb = i >> 10;
  int b = (int)(tb & (BATCH - 1));
  size_t t = tb >> 3;
  out[((size_t)b * TA_SEQ + t) * CH + c] = f2bf(in[i]);
}

// ------------- LayerNorm (eps 1e-6, no affine) + modulate -> bf16 rows -------------
// IN_TBC=1: read from x in [T][B][C] (row permute), also materialize xb (fp32 BTC).
template <int IN_TBC>
__global__ void k_ln_mod(const float* __restrict__ src, const float* __restrict__ mod,
                         u16* __restrict__ out, float* __restrict__ xb_out,
                         int shift_sel, int scale_sel) {
  int row = blockIdx.x;          // 0..B*T-1  (batch-major, b = row>>10)
  int b = row >> 10;
  int tid = threadIdx.x;         // 256
  const float* xr;
  if (IN_TBC) {
    int t = row & (T_SEQ - 1);
    xr = src + ((size_t)t * BATCH + b) * CH;
  } else {
    xr = src + (size_t)row * CH;
  }
  float4 v = reinterpret_cast<const float4*>(xr)[tid];
  float s = v.x + v.y + v.z + v.w;
  float s2 = v.x * v.x + v.y * v.y + v.z * v.z + v.w * v.w;
#pragma unroll
  for (int off = 32; off > 0; off >>= 1) {
    s += __shfl_down(s, off);
    s2 += __shfl_down(s2, off);
  }
  __shared__ float red[8];
  __shared__ float stats[2];
  int wid = tid >> 6;
  if ((tid & 63) == 0) { red[wid] = s; red[4 + wid] = s2; }
  __syncthreads();
  if (tid == 0) {
    float a = red[0] + red[1] + red[2] + red[3];
    float a2 = red[4] + red[5] + red[6] + red[7];
    float mu = a * (1.0f / CH);
    float var = a2 * (1.0f / CH) - mu * mu;
    stats[0] = mu;
    stats[1] = rsqrtf(var + 1e-6f);
  }
  __syncthreads();
  float mu = stats[0], rs = stats[1];
  int c0 = tid * 4;
  if (IN_TBC)
    reinterpret_cast<float4*>(xb_out + (size_t)row * CH)[tid] = v;
  const float* sh = mod + (size_t)b * (6 * CH) + (size_t)shift_sel * CH + c0;
  const float* scl = mod + (size_t)b * (6 * CH) + (size_t)scale_sel * CH + c0;
  float xs[4] = {v.x, v.y, v.z, v.w};
  u16x4 o;
#pragma unroll
  for (int j = 0; j < 4; j++)
    o[j] = f2bf((xs[j] - mu) * rs * (1.0f + scl[j]) + sh[j]);
  *reinterpret_cast<u16x4*>(out + (size_t)row * CH + c0) = o;
}

// ======================= 256x256 8-phase GEMM core (T3+T4+T5) =======================
// Proven in R4. BM=BN=256, BK=64, 8 waves, LDS 128 KiB, counted vmcnt(8), 1 blk/CU.
__device__ __forceinline__ void mfma_quad(const bf16x8 (&af)[4], const bf16x8 (&bfr)[4],
                                          f32x4 (*arow)[4]) {
#pragma unroll
  for (int mi = 0; mi < 4; mi++)
#pragma unroll
    for (int ni = 0; ni < 4; ni++)
      arow[mi][ni] = __builtin_amdgcn_mfma_f32_16x16x32_bf16(af[mi], bfr[ni],
                                                             arow[mi][ni], 0, 0, 0);
}

__device__ __forceinline__ void gemm256_core(
    const u16* __restrict__ A, const u16* __restrict__ Bt, int K,
    int m0, int n0, int tid, u16* AS, u16* BS, f32x4 (&acc)[8][4]) {
  int wid = tid >> 6, lane = tid & 63;
  int wr = wid >> 2, wc = wid & 3;                   // 2 x 4 waves
  int lrow = lane & 15, quad = lane >> 4;
  int sx = (quad ^ ((lrow >> 1) & 3)) * 8;           // read chunk swizzle (u16 units)
  int aRow = wr * 128 + lrow;
  int bRow = wc * 64 + lrow;
  int rA = tid >> 2;
  int qsw = (((tid & 3) ^ ((tid >> 3) & 3)) << 3);   // source chunk swizzle
  const u16* gA = A + (size_t)(m0 + rA) * K + qsw;
  const u16* gB = Bt + (size_t)(n0 + rA) * K + qsw;
  const size_t r128 = (size_t)128 * K;
  u16* dA = AS + tid * 8;
  u16* dB = BS + tid * 8;
  const int NT = K >> 6;                             // 16 for K=1024

#define STGA(dd, hh, tt) do { const u16* s_ = gA + ((tt) * 64 + (hh) * 32); \
    u16* d_ = dA + ((dd) * 2 + (hh)) * 8192; \
    gload_lds16(s_, d_); gload_lds16(s_ + r128, d_ + 4096); } while (0)
#define STGB(dd, hh, tt) do { const u16* s_ = gB + ((tt) * 64 + (hh) * 32); \
    u16* d_ = dB + ((dd) * 2 + (hh)) * 8192; \
    gload_lds16(s_, d_); gload_lds16(s_ + r128, d_ + 4096); } while (0)
#define RD_A(dd, kk, mh) do { const u16* b_ = AS + ((dd) * 2 + (kk)) * 8192; \
    int r_ = aRow + (mh) * 64; \
    af[0] = ldbf8(&b_[(r_) * 32 + sx]); \
    af[1] = ldbf8(&b_[(r_ + 16) * 32 + sx]); \
    af[2] = ldbf8(&b_[(r_ + 32) * 32 + sx]); \
    af[3] = ldbf8(&b_[(r_ + 48) * 32 + sx]); } while (0)
#define RD_B(dd, kk) do { const u16* b_ = BS + ((dd) * 2 + (kk)) * 8192; \
    bfr[0] = ldbf8(&b_[(bRow) * 32 + sx]); \
    bfr[1] = ldbf8(&b_[(bRow + 16) * 32 + sx]); \
    bfr[2] = ldbf8(&b_[(bRow + 32) * 32 + sx]); \
    bfr[3] = ldbf8(&b_[(bRow + 48) * 32 + sx]); } while (0)
#define PHASE_TAIL(mh) do { ASM_LGKM0(); __builtin_amdgcn_sched_barrier(0); \
    __builtin_amdgcn_s_setprio(1); mfma_quad(af, bfr, acc + (mh) * 4); \
    __builtin_amdgcn_s_setprio(0); ASM_BAR(); } while (0)

  // prologue: t0 all 4 halves + t1 k0 halves (6 stages, 12 loads)
  STGA(0, 0, 0); STGB(0, 0, 0); STGA(0, 1, 0); STGB(0, 1, 0);
  STGA(1, 0, 1); STGB(1, 0, 1);
  ASM_VM8(); ASM_BAR();                              // t0 Ak0/Bk0 landed (oldest 4)

  bf16x8 af[4], bfr[4];
  for (int t = 0; t < NT; ++t) {
    int d = t & 1;
    // p0: k0 mh0
    RD_A(d, 0, 0); RD_B(d, 0);
    if (t + 1 < NT) STGA(d ^ 1, 1, t + 1);
    PHASE_TAIL(0);
    // p1: k0 mh1
    RD_A(d, 0, 1);
    if (t + 1 < NT) STGB(d ^ 1, 1, t + 1);
    if (t == NT - 1) { ASM_VM0(); } else { ASM_VM8(); }
    PHASE_TAIL(1);
    // p2: k1 mh0
    RD_A(d, 1, 0); RD_B(d, 1);
    if (t + 2 < NT) STGA(d, 0, t + 2);
    PHASE_TAIL(0);
    // p3: k1 mh1
    RD_A(d, 1, 1);
    if (t + 2 < NT) STGB(d, 0, t + 2);
    if (t < NT - 2) { ASM_VM8(); } else if (t == NT - 2) { ASM_VM4(); }
    PHASE_TAIL(1);
  }
#undef STGA
#undef STGB
#undef RD_A
#undef RD_B
#undef PHASE_TAIL
}

// ------------- 256^2 GEMM, EPI 2 (gelu -> bf16): fc1 -------------
template <int EPI>
__global__ __launch_bounds__(512, 2) void k_gemm256(
    const u16* __restrict__ A, const u16* __restrict__ Bt,
    const float* __restrict__ bias, u16* __restrict__ out_bf,
    float* __restrict__ xb, const float* __restrict__ mod, int gate_sel,
    int M, int N, int K) {
  __shared__ u16 AS[2 * 2 * 8192];
  __shared__ u16 BS[2 * 2 * 8192];
  int m0 = blockIdx.x * 256, n0 = blockIdx.y * 256;
  int tid = threadIdx.x;
  int wid = tid >> 6, lane = tid & 63;
  int wr = wid >> 2, wc = wid & 3;
  int lrow = lane & 15, quad = lane >> 4;
  f32x4 acc[8][4];
#pragma unroll
  for (int mi = 0; mi < 8; mi++)
#pragma unroll
    for (int ni = 0; ni < 4; ni++) acc[mi][ni] = {0.f, 0.f, 0.f, 0.f};
  gemm256_core(A, Bt, K, m0, n0, tid, AS, BS, acc);
#pragma unroll
  for (int mi = 0; mi < 8; mi++)
#pragma unroll
    for (int ni = 0; ni < 4; ni++) {
      int col = n0 + wc * 64 + ni * 16 + lrow;
      float bval = bias[col];
#pragma unroll
      for (int r = 0; r < 4; r++) {
        int row = m0 + wr * 128 + mi * 16 + quad * 4 + r;
        float v = acc[mi][ni][r] + bval;
        if (EPI == 1) {
          int b = row >> 10;
          float g = mod[(size_t)b * (6 * CH) + (size_t)gate_sel * CH + col];
          xb[(size_t)row * N + col] += g * v;
        } else if (EPI == 2) {
          float t2 = 2.3021181302f * (v + 0.044715f * v * v * v);
          float gel = v * __builtin_amdgcn_rcpf(1.0f + exp2f(-t2));
          out_bf[(size_t)row * N + col] = f2bf(gel);
        } else {
          out_bf[(size_t)row * N + col] = f2bf(v * 0.18033688011112042f);
        }
      }
    }
}

// ------------- 256^2 fused QKV GEMM: Bt = [wqT|wkT|wvT] (N=3072) -------------
__global__ __launch_bounds__(512, 2) void k_qkv256(
    const u16* __restrict__ A, const u16* __restrict__ Bt,
    const float* __restrict__ bq, const float* __restrict__ bk,
    const float* __restrict__ bv,
    u16* __restrict__ qout, u16* __restrict__ kout, u16* __restrict__ vt) {
  __shared__ u16 AS[2 * 2 * 8192];
  __shared__ u16 BS[2 * 2 * 8192];
  int m0 = blockIdx.x * 256, n0 = blockIdx.y * 256;
  int tid = threadIdx.x;
  int wid = tid >> 6, lane = tid & 63;
  int wr = wid >> 2, wc = wid & 3;
  int lrow = lane & 15, quad = lane >> 4;
  f32x4 acc[8][4];
#pragma unroll
  for (int mi = 0; mi < 8; mi++)
#pragma unroll
    for (int ni = 0; ni < 4; ni++) acc[mi][ni] = {0.f, 0.f, 0.f, 0.f};
  gemm256_core(A, Bt, CH, m0, n0, tid, AS, BS, acc);
  int seg = n0 >> 10;                     // 256-tile never straddles a 1024 boundary
  const float* bias = (seg == 0) ? bq : (seg == 1) ? bk : bv;
#pragma unroll
  for (int mi = 0; mi < 8; mi++)
#pragma unroll
    for (int ni = 0; ni < 4; ni++) {
      int col = (n0 & 1023) + wc * 64 + ni * 16 + lrow;
      float bval = bias[col];
      int row0 = m0 + wr * 128 + mi * 16 + quad * 4;
      if (seg == 0) {
#pragma unroll
        for (int r = 0; r < 4; r++)
          qout[(size_t)(row0 + r) * CH + col] =
              f2bf((acc[mi][ni][r] + bval) * 0.18033688011112042f);
      } else if (seg == 1) {
#pragma unroll
        for (int r = 0; r < 4; r++)
          kout[(size_t)(row0 + r) * CH + col] = f2bf(acc[mi][ni][r] + bval);
      } else {
        u16x4 pk;
#pragma unroll
        for (int r = 0; r < 4; r++) pk[r] = f2bf(acc[mi][ni][r] + bval);
        int b = row0 >> 10, t0 = row0 & 1023;
        int h = col >> 6, d = col & 63;
        *reinterpret_cast<u16x4*>(
            vt + (((size_t)(b * NH + h) * HD + d) << 10) + t0) = pk;
      }
    }
}

// ------------- 256^2 fused cross K/V GEMM: Bt = [cwkT|cwvT] (N=2048) -------------
__global__ __launch_bounds__(512, 2) void k_kv256(
    const u16* __restrict__ A, const u16* __restrict__ Bt,
    const float* __restrict__ bk, const float* __restrict__ bv,
    u16* __restrict__ kout, u16* __restrict__ vt) {
  __shared__ u16 AS[2 * 2 * 8192];
  __shared__ u16 BS[2 * 2 * 8192];
  int m0 = blockIdx.x * 256, n0 = blockIdx.y * 256;
  int tid = threadIdx.x;
  int wid = tid >> 6, lane = tid & 63;
  int wr = wid >> 2, wc = wid & 3;
  int lrow = lane & 15, quad = lane >> 4;
  f32x4 acc[8][4];
#pragma unroll
  for (int mi = 0; mi < 8; mi++)
#pragma unroll
    for (int ni = 0; ni < 4; ni++) acc[mi][ni] = {0.f, 0.f, 0.f, 0.f};
  gemm256_core(A, Bt, CH, m0, n0, tid, AS, BS, acc);
  int seg = n0 >> 10;
  const float* bias = (seg == 0) ? bk : bv;
#pragma unroll
  for (int mi = 0; mi < 8; mi++)
#pragma unroll
    for (int ni = 0; ni < 4; ni++) {
      int col = (n0 & 1023) + wc * 64 + ni * 16 + lrow;
      float bval = bias[col];
      int row0 = m0 + wr * 128 + mi * 16 + quad * 4;
      if (seg == 0) {
#pragma unroll
        for (int r = 0; r < 4; r++)
          kout[(size_t)(row0 + r) * CH + col] = f2bf(acc[mi][ni][r] + bval);
      } else {
        u16x4 pk;
#pragma unroll
        for (int r = 0; r < 4; r++) pk[r] = f2bf(acc[mi][ni][r] + bval);
        int b = row0 >> 10, t0 = row0 & 1023;
        int h = col >> 6, d = col & 63;
        *reinterpret_cast<u16x4*>(
            vt + (((size_t)(b * NH + h) * HD + d) << 10) + t0) = pk;
      }
    }
}

// ============ 256x128 8-phase GEMM core v3: 4x2 waves (64x64 tiles) ================
// For N=1024 GEMMs (wo/cq/cwo/fc2). Same stage schedule / vmcnt ledger / barrier
// count as the PROVEN v1 core — only the wave decomposition changes.
// LDS-read traffic model: per K-tile = BK*2B*Sum(waveM+waveN). v1's 2x4 split
// (128x32 tiles) = 20 reads/wave = 160KB/K-tile (~1930cy @85B/cy = 53% of measured
// 3670cy K-tile). v3's 4x2 split (64x64 tiles) minimizes the sum: 16 reads/wave
// = 128KB/K-tile (-20%). Phases: p0 {A4+B2(nh0), 8 MFMA}, p1 {B2(nh1), A reused,
// 8 MFMA}, p2/p3 same for k1. All frag rows remain lrow mod 16 -> the verified
// swizzle algebra (chunk ^ ((row>>1)&3)) is unchanged; conflicts stay 0.
// WAR: A(d,k0) last read t.p0, restaged t.p2 (>=2 barriers); B(d,k0) last read
// t.p1, restaged t.p3; (d^1,k1) regions last read (t-1).p2/p3, restaged t.p0/p1.
template <int NB>
__device__ __forceinline__ void mfma_col2(const bf16x8 (&af)[4], const bf16x8 (&bfr)[2],
                                          f32x4 (&acc)[4][4]) {
#pragma unroll
  for (int mi = 0; mi < 4; mi++)
#pragma unroll
    for (int j = 0; j < 2; j++)
      acc[mi][NB + j] = __builtin_amdgcn_mfma_f32_16x16x32_bf16(af[mi], bfr[j],
                                                                acc[mi][NB + j], 0, 0, 0);
}

__device__ __forceinline__ void gemm128n_core(
    const u16* __restrict__ A, const u16* __restrict__ Bt, int K,
    int m0, int n0, int tid, u16* AS, u16* BS, f32x4 (&acc)[4][4]) {
  int wid = tid >> 6, lane = tid & 63;
  int wr = wid >> 1, wc = wid & 1;                   // 4M x 2N waves (64 x 64 each)
  int lrow = lane & 15, quad = lane >> 4;
  int sx = (quad ^ ((lrow >> 1) & 3)) * 8;
  int aRow = wr * 64 + lrow;
  int bRow = wc * 64 + lrow;
  int rA = tid >> 2;                                 // 0..127
  int qsw = (((tid & 3) ^ ((tid >> 3) & 3)) << 3);
  const u16* gA = A + (size_t)(m0 + rA) * K + qsw;
  const u16* gB = Bt + (size_t)(n0 + rA) * K + qsw;  // B tile: exactly 128 rows
  const size_t r128 = (size_t)128 * K;
  u16* dA = AS + tid * 8;
  u16* dB = BS + tid * 8;
  const int NT = K >> 6;                             // 16 (K=1024) or 64 (K=4096)

#define STGA(dd, hh, tt) do { const u16* s_ = gA + ((tt) * 64 + (hh) * 32); \
    u16* d_ = dA + ((dd) * 2 + (hh)) * 8192; \
    gload_lds16(s_, d_); gload_lds16(s_ + r128, d_ + 4096); } while (0)
#define STGB(dd, hh, tt) do { const u16* s_ = gB + ((tt) * 64 + (hh) * 32); \
    u16* d_ = dB + ((dd) * 2 + (hh)) * 4096; \
    gload_lds16(s_, d_); } while (0)
#define RD_A4(dd, kk) do { const u16* b_ = AS + ((dd) * 2 + (kk)) * 8192; \
    af[0] = ldbf8(&b_[(aRow) * 32 + sx]); \
    af[1] = ldbf8(&b_[(aRow + 16) * 32 + sx]); \
    af[2] = ldbf8(&b_[(aRow + 32) * 32 + sx]); \
    af[3] = ldbf8(&b_[(aRow + 48) * 32 + sx]); } while (0)
#define RD_B2(dd, kk, nh) do { const u16* b_ = BS + ((dd) * 2 + (kk)) * 4096; \
    int r_ = bRow + (nh) * 32; \
    bfr[0] = ldbf8(&b_[(r_) * 32 + sx]); \
    bfr[1] = ldbf8(&b_[(r_ + 16) * 32 + sx]); } while (0)
#define PHASE_TAIL(NBv) do { ASM_LGKM0(); __builtin_amdgcn_sched_barrier(0); \
    __builtin_amdgcn_s_setprio(1); mfma_col2<NBv>(af, bfr, acc); \
    __builtin_amdgcn_s_setprio(0); ASM_BAR(); } while (0)

  // prologue: 9 loads; t0k0 = oldest 3 (ledger identical to proven v1)
  STGA(0, 0, 0); STGB(0, 0, 0); STGA(0, 1, 0); STGB(0, 1, 0);
  STGA(1, 0, 1); STGB(1, 0, 1);
  ASM_VM6(); ASM_BAR();

  bf16x8 af[4], bfr[2];
  for (int t = 0; t < NT; ++t) {
    int d = t & 1;
    // p0: k0, A frags + B n-half0
    RD_A4(d, 0); RD_B2(d, 0, 0);
    if (t + 1 < NT) STGA(d ^ 1, 1, t + 1);
    PHASE_TAIL(0);
    // p1: k0, B n-half1 (A reused in registers)
    RD_B2(d, 0, 1);
    if (t + 1 < NT) STGB(d ^ 1, 1, t + 1);
    if (t == NT - 1) { ASM_VM0(); } else { ASM_VM6(); }
    PHASE_TAIL(2);
    // p2: k1, A frags + B n-half0
    RD_A4(d, 1); RD_B2(d, 1, 0);
    if (t + 2 < NT) STGA(d, 0, t + 2);
    PHASE_TAIL(0);
    // p3: k1, B n-half1
    RD_B2(d, 1, 1);
    if (t + 2 < NT) STGB(d, 0, t + 2);
    if (t < NT - 2) { ASM_VM6(); } else if (t == NT - 2) { ASM_VM3(); }
    PHASE_TAIL(2);
  }
#undef STGA
#undef STGB
#undef RD_A4
#undef RD_B2
#undef PHASE_TAIL
}

// ------------- 256x128 GEMM with fused epilogues -------------
// EPI 1: xb += mod[gate] * (acc+bias)
// EPI 3: out_bf = bf16((acc+bias) * 0.125*log2e)
// EPI 4: final fc2: dout[TBC-permuted] = xb + mod[gate]*(acc+bias)
template <int EPI>
__global__ __launch_bounds__(512, 2) void k_gemm128n(
    const u16* __restrict__ A, const u16* __restrict__ Bt,
    const float* __restrict__ bias, u16* __restrict__ out_bf,
    float* __restrict__ xb, float* __restrict__ dout,
    const float* __restrict__ mod, int gate_sel, int M, int N, int K) {
  __shared__ u16 AS[2 * 2 * 8192];
  __shared__ u16 BS[2 * 2 * 4096];
  int m0 = blockIdx.x * 256, n0 = blockIdx.y * 128;
  int tid = threadIdx.x;
  int wid = tid >> 6, lane = tid & 63;
  int wr = wid >> 1, wc = wid & 1;
  int lrow = lane & 15, quad = lane >> 4;
  f32x4 acc[4][4];
#pragma unroll
  for (int mi = 0; mi < 4; mi++)
#pragma unroll
    for (int ni = 0; ni < 4; ni++) acc[mi][ni] = {0.f, 0.f, 0.f, 0.f};
  gemm128n_core(A, Bt, K, m0, n0, tid, AS, BS, acc);
#pragma unroll
  for (int mi = 0; mi < 4; mi++)
#pragma unroll
    for (int ni = 0; ni < 4; ni++) {
      int col = n0 + wc * 64 + ni * 16 + lrow;
      float bval = bias[col];
#pragma unroll
      for (int r = 0; r < 4; r++) {
        int row = m0 + wr * 64 + mi * 16 + quad * 4 + r;
        float v = acc[mi][ni][r] + bval;
        if (EPI == 1) {
          int b = row >> 10;
          float g = mod[(size_t)b * (6 * CH) + (size_t)gate_sel * CH + col];
          xb[(size_t)row * N + col] += g * v;
        } else if (EPI == 3) {
          out_bf[(size_t)row * N + col] = f2bf(v * 0.18033688011112042f);
        } else {   // EPI 4
          int b = row >> 10, t = row & (T_SEQ - 1);
          float g = mod[(size_t)b * (6 * CH) + (size_t)gate_sel * CH + col];
          dout[((size_t)t * BATCH + b) * CH + col] =
              xb[(size_t)row * N + col] + g * v;
        }
      }
    }
}

// ------------- flash attention v4: 64 q-rows per WAVE, barrier-free ----------------
__global__ __launch_bounds__(256, 2) void k_attn(
    const u16* __restrict__ Q, const u16* __restrict__ Kb,
    const u16* __restrict__ vt, const int* __restrict__ mask,
    u16* __restrict__ Y) {
  int qt = blockIdx.x, h = blockIdx.y, b = blockIdx.z;
  int tid = threadIdx.x, wid = tid >> 6, lane = tid & 63;
  int lrow = lane & 15, quad = lane >> 4;
  int qbase = qt * 256 + wid * 64;     // wave's 64 q-rows

  __shared__ u16 P[4][4][16][72];      // [wave][subtile][qrow][key] wave-private

  bf16x8 aq[4][2];
#pragma unroll
  for (int st = 0; st < 4; st++) {
    size_t qoff = ((size_t)(b * T_SEQ + qbase + st * 16 + lrow)) * CH + h * HD;
    aq[st][0] = ldbf8(Q + qoff + quad * 8);
    aq[st][1] = ldbf8(Q + qoff + 32 + quad * 8);
  }

  u16x8 uo;
#pragma unroll
  for (int j = 0; j < 8; j++) uo[j] = (lrow == 0) ? (u16)0x3F80 : (u16)0;
  bf16x8 ones = __builtin_bit_cast(bf16x8, uo);

  const int* mrow = mask + (size_t)b * T_SEQ;
  const u16* ksrc = Kb + ((size_t)(b * T_SEQ) + lrow) * CH + h * HD + quad * 8;
  const u16* vsrc = vt + (((size_t)(b * NH + h) * HD + lrow) << 10) + quad * 8;

  f32x4 o[4][5];
#pragma unroll
  for (int st = 0; st < 4; st++)
#pragma unroll
    for (int dc = 0; dc < 5; dc++) o[st][dc] = {0.f, 0.f, 0.f, 0.f};

  for (int kt = 0; kt < 16; kt++) {
    int kb = kt * 64;
    bf16x8 kf[8];
    float mb[4];
#pragma unroll
    for (int sub = 0; sub < 4; sub++) {
      const u16* kp = ksrc + (size_t)(kb + sub * 16) * CH;
      kf[sub * 2] = ldbf8(kp);
      kf[sub * 2 + 1] = ldbf8(kp + 32);
      mb[sub] = mrow[kb + sub * 16 + lrow] ? -INFINITY : 0.0f;
    }
    bf16x8 vf[8];
#pragma unroll
    for (int dc = 0; dc < 4; dc++) {
      const u16* vp = vsrc + (size_t)(dc * 16) * 1024 + kb;
      vf[dc * 2] = ldbf8(vp);
      vf[dc * 2 + 1] = ldbf8(vp + 32);
    }
#pragma unroll
    for (int st = 0; st < 4; st++) {
#pragma unroll
      for (int sub = 0; sub < 4; sub++) {
        f32x4 z = {0.f, 0.f, 0.f, 0.f};
        z = __builtin_amdgcn_mfma_f32_16x16x32_bf16(aq[st][0], kf[sub * 2], z, 0, 0, 0);
        z = __builtin_amdgcn_mfma_f32_16x16x32_bf16(aq[st][1], kf[sub * 2 + 1], z, 0, 0, 0);
        float mbv = mb[sub];
#pragma unroll
        for (int r = 0; r < 4; r++) {
          float p = exp2f(z[r] + mbv);   // exp2(-inf) = 0 handles masking
          P[wid][st][quad * 4 + r][sub * 16 + lrow] = f2bf_trunc(p);
        }
      }
    }
#pragma unroll
    for (int st = 0; st < 4; st++) {
      bf16x8 pf0 = ldbf8(&P[wid][st][lrow][quad * 8]);
      bf16x8 pf1 = ldbf8(&P[wid][st][lrow][32 + quad * 8]);
#pragma unroll
      for (int dc = 0; dc < 4; dc++) {
        o[st][dc] = __builtin_amdgcn_mfma_f32_16x16x32_bf16(pf0, vf[dc * 2], o[st][dc], 0, 0, 0);
        o[st][dc] = __builtin_amdgcn_mfma_f32_16x16x32_bf16(pf1, vf[dc * 2 + 1], o[st][dc], 0, 0, 0);
      }
      o[st][4] = __builtin_amdgcn_mfma_f32_16x16x32_bf16(pf0, ones, o[st][4], 0, 0, 0);
      o[st][4] = __builtin_amdgcn_mfma_f32_16x16x32_bf16(pf1, ones, o[st][4], 0, 0, 0);
    }
  }

#pragma unroll
  for (int st = 0; st < 4; st++)
#pragma unroll
    for (int r = 0; r < 4; r++) {
      float l = __shfl(o[st][4][r], lane & 48);
      float linv = 1.0f / l;
      int qr = qbase + st * 16 + quad * 4 + r;
      size_t yo = ((size_t)(b * T_SEQ + qr)) * CH + h * HD;
#pragma unroll
      for (int dc = 0; dc < 4; dc++)
        Y[yo + dc * 16 + lrow] = f2bf(o[st][dc][r] * linv);
    }
}

extern "C" void kernel_launch(void* const* d_in, const int* in_sizes, int n_in,
                              void* d_out, int out_size, void* d_ws, size_t ws_size,
                              hipStream_t stream) {
  const float* x     = (const float*)d_in[0];
  const float* c     = (const float*)d_in[1];
  const int*   pmask = (const int*)d_in[2];
  const float* audio = (const float*)d_in[3];
  const int*   amask = (const int*)d_in[4];
  const float* w_ada = (const float*)d_in[5];
  const float* b_ada = (const float*)d_in[6];
  const float* wq = (const float*)d_in[7];  const float* bq = (const float*)d_in[8];
  const float* wk = (const float*)d_in[9];  const float* bk = (const float*)d_in[10];
  const float* wv = (const float*)d_in[11]; const float* bv = (const float*)d_in[12];
  const float* wo = (const float*)d_in[13]; const float* bo = (const float*)d_in[14];
  const float* cwq = (const float*)d_in[15]; const float* cbq = (const float*)d_in[16];
  const float* cwk = (const float*)d_in[17]; const float* cbk = (const float*)d_in[18];
  const float* cwv = (const float*)d_in[19]; const float* cbv = (const float*)d_in[20];
  const float* cwo = (const float*)d_in[21]; const float* cbo = (const float*)d_in[22];
  const float* w1 = (const float*)d_in[23]; const float* b1 = (const float*)d_in[24];
  const float* w2 = (const float*)d_in[25]; const float* b2 = (const float*)d_in[26];

  char* wsb = (char*)d_ws;
  size_t off = 0;
  auto alloc = [&](size_t bytes) {
    char* p = wsb + off;
    off += (bytes + 255) & ~(size_t)255;
    return p;
  };
  const size_t SQ = (size_t)CH * CH * 2;       // 2MB bf16 square weight
  u16* wqT  = (u16*)alloc(SQ);                 // wqT|wkT|wvT contiguous = QKV Bt
  u16* wkT  = (u16*)alloc(SQ);
  u16* wvT  = (u16*)alloc(SQ);
  u16* woT  = (u16*)alloc(SQ);
  u16* cwqT = (u16*)alloc(SQ);
  u16* cwkT = (u16*)alloc(SQ);                 // cwkT|cwvT contiguous = KV Bt
  u16* cwvT = (u16*)alloc(SQ);
  u16* cwoT = (u16*)alloc(SQ);
  u16* w1T  = (u16*)alloc((size_t)CH * MH * 2);
  u16* w2T  = (u16*)alloc((size_t)CH * MH * 2);
  float* mod = (float*)alloc((size_t)BATCH * 6 * CH * 4);
  float* xb  = (float*)alloc((size_t)BATCH * T_SEQ * CH * 4);
  u16* xm    = (u16*)alloc((size_t)BATCH * T_SEQ * CH * 2);
  u16* hbuf  = (u16*)alloc((size_t)BATCH * T_SEQ * MH * 2);
  u16* qbuf  = hbuf;
  u16* kbuf  = hbuf + (size_t)BATCH * T_SEQ * CH;
  u16* ybuf  = hbuf + (size_t)2 * BATCH * T_SEQ * CH;
  u16* vt    = hbuf + (size_t)3 * BATCH * T_SEQ * CH;
  u16* abuf  = (u16*)alloc((size_t)BATCH * TA_SEQ * CH * 2);
  (void)ws_size; (void)in_sizes; (void)n_in; (void)out_size;

  const int NE = T_SEQ * BATCH * CH;   // 8.39M elements
  dim3 tb32(32, 8);

  P8f src8; P8u dst8;
  src8.p[0] = wq;  dst8.p[0] = wqT;
  src8.p[1] = wk;  dst8.p[1] = wkT;
  src8.p[2] = wv;  dst8.p[2] = wvT;
  src8.p[3] = wo;  dst8.p[3] = woT;
  src8.p[4] = cwq; dst8.p[4] = cwqT;
  src8.p[5] = cwk; dst8.p[5] = cwkT;
  src8.p[6] = cwv; dst8.p[6] = cwvT;
  src8.p[7] = cwo; dst8.p[7] = cwoT;
  k_transpose8<<<dim3(CH / 32, CH / 32, 8), tb32, 0, stream>>>(src8, dst8);
  k_transpose_w<<<dim3(MH / 32, CH / 32), tb32, 0, stream>>>(w1, w1T, CH, MH);
  k_transpose_w<<<dim3(CH / 32, MH / 32), tb32, 0, stream>>>(w2, w2T, MH, CH);

  k_ada<<<dim3(6 * CH / 256, BATCH), 256, 0, stream>>>(c, w_ada, b_ada, mod);
  k_tbc_to_btc_bf16<<<NE / 256, 256, 0, stream>>>(audio, abuf);

  // ---- self-attention ----
  // fused: x(TBC) -> xb(BTC fp32) + LN+mod -> xm
  k_ln_mod<1><<<BATCH * T_SEQ, 256, 0, stream>>>(x, mod, xm, xb, 0, 1);
  k_qkv256<<<dim3(32, 12), 512, 0, stream>>>(xm, wqT, bq, bk, bv, qbuf, kbuf, vt);
  k_attn<<<dim3(T_SEQ / 256, NH, BATCH), 256, 0, stream>>>(qbuf, kbuf, vt, pmask, ybuf);
  k_gemm128n<1><<<dim3(32, 8), 512, 0, stream>>>(ybuf, woT, bo, nullptr, xb, nullptr, mod, 2, 8192, CH, CH);

  // ---- cross-attention (reuses msa shift/scale/gate) ----
  k_ln_mod<0><<<BATCH * T_SEQ, 256, 0, stream>>>(xb, mod, xm, nullptr, 0, 1);
  k_gemm128n<3><<<dim3(32, 8), 512, 0, stream>>>(xm, cwqT, cbq, qbuf, nullptr, nullptr, nullptr, 0, 8192, CH, CH);
  k_kv256<<<dim3(32, 8), 512, 0, stream>>>(abuf, cwkT, cbk, cbv, kbuf, vt);
  k_attn<<<dim3(T_SEQ / 256, NH, BATCH), 256, 0, stream>>>(qbuf, kbuf, vt, amask, ybuf);
  k_gemm128n<1><<<dim3(32, 8), 512, 0, stream>>>(ybuf, cwoT, cbo, nullptr, xb, nullptr, mod, 2, 8192, CH, CH);

  // ---- MLP ----
  k_ln_mod<0><<<BATCH * T_SEQ, 256, 0, stream>>>(xb, mod, xm, nullptr, 3, 4);
  k_gemm256<2><<<dim3(32, 16), 512, 0, stream>>>(xm, w1T, b1, hbuf, nullptr, nullptr, 0, 8192, MH, CH);
  // fc2 writes d_out directly in [T][B][C]
  k_gemm128n<4><<<dim3(32, 8), 512, 0, stream>>>(hbuf, w2T, b2, nullptr, xb, (float*)d_out, mod, 5, 8192, CH, MH);
}

// Round 10
// 830.216 us; speedup vs baseline: 1.0341x; 1.0341x over previous
//
#include <hip/hip_runtime.h>
#include <math.h>

#define T_SEQ 1024
#define TA_SEQ 1024
#define BATCH 8
#define CH 1024
#define NH 16
#define HD 64
#define MH 4096

typedef unsigned short u16;
typedef unsigned short u16x4 __attribute__((ext_vector_type(4)));
typedef unsigned short u16x8 __attribute__((ext_vector_type(8)));
typedef __bf16 bf16x8 __attribute__((ext_vector_type(8)));
typedef float f32x4 __attribute__((ext_vector_type(4)));

__device__ __forceinline__ u16 f2bf(float f) {
  unsigned int u = __builtin_bit_cast(unsigned int, f);
  u += 0x7FFFu + ((u >> 16) & 1u);   // RNE
  return (u16)(u >> 16);
}
__device__ __forceinline__ u16 f2bf_trunc(float f) {   // cheap cvt for P (p >= 0)
  return (u16)(__builtin_bit_cast(unsigned int, f) >> 16);
}
__device__ __forceinline__ bf16x8 ldbf8(const u16* p) {
  return __builtin_bit_cast(bf16x8, *reinterpret_cast<const u16x8*>(p));
}
// async global->LDS, 16B per lane (dest must be wave-uniform base + lane*16)
__device__ __forceinline__ void gload_lds16(const u16* g, u16* l) {
  __builtin_amdgcn_global_load_lds(
      (const __attribute__((address_space(1))) unsigned int*)g,
      (__attribute__((address_space(3))) unsigned int*)l, 16, 0, 0);
}

// raw barrier / counted waits (T4: never drain vmcnt(0) in the main loop).
// "memory" clobber pins all C++ memory ops (builtin s_barrier is NOT a fence).
#define ASM_BAR()   asm volatile("s_barrier" ::: "memory")
#define ASM_VM8()   asm volatile("s_waitcnt vmcnt(8)" ::: "memory")
#define ASM_VM6()   asm volatile("s_waitcnt vmcnt(6)" ::: "memory")
#define ASM_VM4()   asm volatile("s_waitcnt vmcnt(4)" ::: "memory")
#define ASM_VM3()   asm volatile("s_waitcnt vmcnt(3)" ::: "memory")
#define ASM_VM0()   asm volatile("s_waitcnt vmcnt(0)" ::: "memory")
#define ASM_LGKM0() asm volatile("s_waitcnt lgkmcnt(0)" ::: "memory")

// ------------- weight transpose-convert: fp32 in[K][N] -> bf16 out[N][K] -------------
__global__ void k_transpose_w(const float* __restrict__ in, u16* __restrict__ out,
                              int K, int N) {
  __shared__ float tile[32][33];
  int n0 = blockIdx.x * 32, k0 = blockIdx.y * 32;
  int tx = threadIdx.x, ty = threadIdx.y;   // block (32,8)
#pragma unroll
  for (int i = 0; i < 4; i++)
    tile[ty + i * 8][tx] = in[(size_t)(k0 + ty + i * 8) * N + n0 + tx];
  __syncthreads();
#pragma unroll
  for (int i = 0; i < 4; i++)
    out[(size_t)(n0 + ty + i * 8) * K + k0 + tx] = f2bf(tile[tx][ty + i * 8]);
}

// batched version for the 8 square (1024x1024) weights: one dispatch, blockIdx.z selects
struct P8f { const float* p[8]; };
struct P8u { u16* p[8]; };
__global__ void k_transpose8(P8f in8, P8u out8) {
  const float* __restrict__ in = in8.p[blockIdx.z];
  u16* __restrict__ out = out8.p[blockIdx.z];
  __shared__ float tile[32][33];
  int n0 = blockIdx.x * 32, k0 = blockIdx.y * 32;
  int tx = threadIdx.x, ty = threadIdx.y;   // block (32,8)
#pragma unroll
  for (int i = 0; i < 4; i++)
    tile[ty + i * 8][tx] = in[(size_t)(k0 + ty + i * 8) * CH + n0 + tx];
  __syncthreads();
#pragma unroll
  for (int i = 0; i < 4; i++)
    out[(size_t)(n0 + ty + i * 8) * CH + k0 + tx] = f2bf(tile[tx][ty + i * 8]);
}

// ------------- adaLN modulation: mod[b][6C] = silu(c[b]) @ w_ada + b_ada -------------
__global__ void k_ada(const float* __restrict__ c, const float* __restrict__ w_ada,
                      const float* __restrict__ b_ada, float* __restrict__ mod) {
  __shared__ float sc[CH];
  int b = blockIdx.y;
  int tid = threadIdx.x;
  for (int i = tid; i < CH; i += 256) {
    float cv = c[b * CH + i];
    sc[i] = cv / (1.0f + expf(-cv));   // silu
  }
  __syncthreads();
  int n = blockIdx.x * 256 + tid;
  float acc = 0.0f;
  for (int k = 0; k < CH; k++) acc += sc[k] * w_ada[(size_t)k * (6 * CH) + n];
  mod[(size_t)b * (6 * CH) + n] = acc + b_ada[n];
}

// ------------- audio [TA][B][C] fp32 -> batch-major [B*TA][C] bf16 -------------
__global__ void k_tbc_to_btc_bf16(const float* __restrict__ in, u16* __restrict__ out) {
  size_t i = (size_t)blockIdx.x * 256 + threadIdx.x;
  int c = (int)(i & (CH - 1));
  size_t tb = i >> 10;
  int b = (int)(tb & (BATCH - 1));
  size_t t = tb >> 3;
  out[((size_t)b * TA_SEQ + t) * CH + c] = f2bf(in[i]);
}

// ------------- LayerNorm (eps 1e-6, no affine) + modulate -> bf16 rows -------------
// IN_TBC=1: read from x in [T][B][C] (row permute), also materialize xb (fp32 BTC).
template <int IN_TBC>
__global__ void k_ln_mod(const float* __restrict__ src, const float* __restrict__ mod,
                         u16* __restrict__ out, float* __restrict__ xb_out,
                         int shift_sel, int scale_sel) {
  int row = blockIdx.x;          // 0..B*T-1  (batch-major, b = row>>10)
  int b = row >> 10;
  int tid = threadIdx.x;         // 256
  const float* xr;
  if (IN_TBC) {
    int t = row & (T_SEQ - 1);
    xr = src + ((size_t)t * BATCH + b) * CH;
  } else {
    xr = src + (size_t)row * CH;
  }
  float4 v = reinterpret_cast<const float4*>(xr)[tid];
  float s = v.x + v.y + v.z + v.w;
  float s2 = v.x * v.x + v.y * v.y + v.z * v.z + v.w * v.w;
#pragma unroll
  for (int off = 32; off > 0; off >>= 1) {
    s += __shfl_down(s, off);
    s2 += __shfl_down(s2, off);
  }
  __shared__ float red[8];
  __shared__ float stats[2];
  int wid = tid >> 6;
  if ((tid & 63) == 0) { red[wid] = s; red[4 + wid] = s2; }
  __syncthreads();
  if (tid == 0) {
    float a = red[0] + red[1] + red[2] + red[3];
    float a2 = red[4] + red[5] + red[6] + red[7];
    float mu = a * (1.0f / CH);
    float var = a2 * (1.0f / CH) - mu * mu;
    stats[0] = mu;
    stats[1] = rsqrtf(var + 1e-6f);
  }
  __syncthreads();
  float mu = stats[0], rs = stats[1];
  int c0 = tid * 4;
  if (IN_TBC)
    reinterpret_cast<float4*>(xb_out + (size_t)row * CH)[tid] = v;
  const float* sh = mod + (size_t)b * (6 * CH) + (size_t)shift_sel * CH + c0;
  const float* scl = mod + (size_t)b * (6 * CH) + (size_t)scale_sel * CH + c0;
  float xs[4] = {v.x, v.y, v.z, v.w};
  u16x4 o;
#pragma unroll
  for (int j = 0; j < 4; j++)
    o[j] = f2bf((xs[j] - mu) * rs * (1.0f + scl[j]) + sh[j]);
  *reinterpret_cast<u16x4*>(out + (size_t)row * CH + c0) = o;
}

// ======================= 256x256 8-phase GEMM core (T3+T4+T5) =======================
// Proven in R4. BM=BN=256, BK=64, 8 waves, LDS 128 KiB, counted vmcnt(8), 1 blk/CU.
__device__ __forceinline__ void mfma_quad(const bf16x8 (&af)[4], const bf16x8 (&bfr)[4],
                                          f32x4 (*arow)[4]) {
#pragma unroll
  for (int mi = 0; mi < 4; mi++)
#pragma unroll
    for (int ni = 0; ni < 4; ni++)
      arow[mi][ni] = __builtin_amdgcn_mfma_f32_16x16x32_bf16(af[mi], bfr[ni],
                                                             arow[mi][ni], 0, 0, 0);
}

__device__ __forceinline__ void gemm256_core(
    const u16* __restrict__ A, const u16* __restrict__ Bt, int K,
    int m0, int n0, int tid, u16* AS, u16* BS, f32x4 (&acc)[8][4]) {
  int wid = tid >> 6, lane = tid & 63;
  int wr = wid >> 2, wc = wid & 3;                   // 2 x 4 waves
  int lrow = lane & 15, quad = lane >> 4;
  int sx = (quad ^ ((lrow >> 1) & 3)) * 8;           // read chunk swizzle (u16 units)
  int aRow = wr * 128 + lrow;
  int bRow = wc * 64 + lrow;
  int rA = tid >> 2;
  int qsw = (((tid & 3) ^ ((tid >> 3) & 3)) << 3);   // source chunk swizzle
  const u16* gA = A + (size_t)(m0 + rA) * K + qsw;
  const u16* gB = Bt + (size_t)(n0 + rA) * K + qsw;
  const size_t r128 = (size_t)128 * K;
  u16* dA = AS + tid * 8;
  u16* dB = BS + tid * 8;
  const int NT = K >> 6;                             // 16 for K=1024

#define STGA(dd, hh, tt) do { const u16* s_ = gA + ((tt) * 64 + (hh) * 32); \
    u16* d_ = dA + ((dd) * 2 + (hh)) * 8192; \
    gload_lds16(s_, d_); gload_lds16(s_ + r128, d_ + 4096); } while (0)
#define STGB(dd, hh, tt) do { const u16* s_ = gB + ((tt) * 64 + (hh) * 32); \
    u16* d_ = dB + ((dd) * 2 + (hh)) * 8192; \
    gload_lds16(s_, d_); gload_lds16(s_ + r128, d_ + 4096); } while (0)
#define RD_A(dd, kk, mh) do { const u16* b_ = AS + ((dd) * 2 + (kk)) * 8192; \
    int r_ = aRow + (mh) * 64; \
    af[0] = ldbf8(&b_[(r_) * 32 + sx]); \
    af[1] = ldbf8(&b_[(r_ + 16) * 32 + sx]); \
    af[2] = ldbf8(&b_[(r_ + 32) * 32 + sx]); \
    af[3] = ldbf8(&b_[(r_ + 48) * 32 + sx]); } while (0)
#define RD_B(dd, kk) do { const u16* b_ = BS + ((dd) * 2 + (kk)) * 8192; \
    bfr[0] = ldbf8(&b_[(bRow) * 32 + sx]); \
    bfr[1] = ldbf8(&b_[(bRow + 16) * 32 + sx]); \
    bfr[2] = ldbf8(&b_[(bRow + 32) * 32 + sx]); \
    bfr[3] = ldbf8(&b_[(bRow + 48) * 32 + sx]); } while (0)
#define PHASE_TAIL(mh) do { ASM_LGKM0(); __builtin_amdgcn_sched_barrier(0); \
    __builtin_amdgcn_s_setprio(1); mfma_quad(af, bfr, acc + (mh) * 4); \
    __builtin_amdgcn_s_setprio(0); ASM_BAR(); } while (0)

  // prologue: t0 all 4 halves + t1 k0 halves (6 stages, 12 loads)
  STGA(0, 0, 0); STGB(0, 0, 0); STGA(0, 1, 0); STGB(0, 1, 0);
  STGA(1, 0, 1); STGB(1, 0, 1);
  ASM_VM8(); ASM_BAR();                              // t0 Ak0/Bk0 landed (oldest 4)

  bf16x8 af[4], bfr[4];
  for (int t = 0; t < NT; ++t) {
    int d = t & 1;
    // p0: k0 mh0
    RD_A(d, 0, 0); RD_B(d, 0);
    if (t + 1 < NT) STGA(d ^ 1, 1, t + 1);
    PHASE_TAIL(0);
    // p1: k0 mh1
    RD_A(d, 0, 1);
    if (t + 1 < NT) STGB(d ^ 1, 1, t + 1);
    if (t == NT - 1) { ASM_VM0(); } else { ASM_VM8(); }
    PHASE_TAIL(1);
    // p2: k1 mh0
    RD_A(d, 1, 0); RD_B(d, 1);
    if (t + 2 < NT) STGA(d, 0, t + 2);
    PHASE_TAIL(0);
    // p3: k1 mh1
    RD_A(d, 1, 1);
    if (t + 2 < NT) STGB(d, 0, t + 2);
    if (t < NT - 2) { ASM_VM8(); } else if (t == NT - 2) { ASM_VM4(); }
    PHASE_TAIL(1);
  }
#undef STGA
#undef STGB
#undef RD_A
#undef RD_B
#undef PHASE_TAIL
}

// ------------- 256^2 GEMM, EPI 2 (gelu -> bf16): fc1 -------------
template <int EPI>
__global__ __launch_bounds__(512, 2) void k_gemm256(
    const u16* __restrict__ A, const u16* __restrict__ Bt,
    const float* __restrict__ bias, u16* __restrict__ out_bf,
    float* __restrict__ xb, const float* __restrict__ mod, int gate_sel,
    int M, int N, int K) {
  __shared__ u16 AS[2 * 2 * 8192];
  __shared__ u16 BS[2 * 2 * 8192];
  int m0 = blockIdx.x * 256, n0 = blockIdx.y * 256;
  int tid = threadIdx.x;
  int wid = tid >> 6, lane = tid & 63;
  int wr = wid >> 2, wc = wid & 3;
  int lrow = lane & 15, quad = lane >> 4;
  f32x4 acc[8][4];
#pragma unroll
  for (int mi = 0; mi < 8; mi++)
#pragma unroll
    for (int ni = 0; ni < 4; ni++) acc[mi][ni] = {0.f, 0.f, 0.f, 0.f};
  gemm256_core(A, Bt, K, m0, n0, tid, AS, BS, acc);
#pragma unroll
  for (int mi = 0; mi < 8; mi++)
#pragma unroll
    for (int ni = 0; ni < 4; ni++) {
      int col = n0 + wc * 64 + ni * 16 + lrow;
      float bval = bias[col];
#pragma unroll
      for (int r = 0; r < 4; r++) {
        int row = m0 + wr * 128 + mi * 16 + quad * 4 + r;
        float v = acc[mi][ni][r] + bval;
        if (EPI == 1) {
          int b = row >> 10;
          float g = mod[(size_t)b * (6 * CH) + (size_t)gate_sel * CH + col];
          xb[(size_t)row * N + col] += g * v;
        } else if (EPI == 2) {
          float t2 = 2.3021181302f * (v + 0.044715f * v * v * v);
          float gel = v * __builtin_amdgcn_rcpf(1.0f + exp2f(-t2));
          out_bf[(size_t)row * N + col] = f2bf(gel);
        } else {
          out_bf[(size_t)row * N + col] = f2bf(v * 0.18033688011112042f);
        }
      }
    }
}

// ------------- 256^2 fused QKV GEMM: Bt = [wqT|wkT|wvT] (N=3072) -------------
__global__ __launch_bounds__(512, 2) void k_qkv256(
    const u16* __restrict__ A, const u16* __restrict__ Bt,
    const float* __restrict__ bq, const float* __restrict__ bk,
    const float* __restrict__ bv,
    u16* __restrict__ qout, u16* __restrict__ kout, u16* __restrict__ vt) {
  __shared__ u16 AS[2 * 2 * 8192];
  __shared__ u16 BS[2 * 2 * 8192];
  int m0 = blockIdx.x * 256, n0 = blockIdx.y * 256;
  int tid = threadIdx.x;
  int wid = tid >> 6, lane = tid & 63;
  int wr = wid >> 2, wc = wid & 3;
  int lrow = lane & 15, quad = lane >> 4;
  f32x4 acc[8][4];
#pragma unroll
  for (int mi = 0; mi < 8; mi++)
#pragma unroll
    for (int ni = 0; ni < 4; ni++) acc[mi][ni] = {0.f, 0.f, 0.f, 0.f};
  gemm256_core(A, Bt, CH, m0, n0, tid, AS, BS, acc);
  int seg = n0 >> 10;                     // 256-tile never straddles a 1024 boundary
  const float* bias = (seg == 0) ? bq : (seg == 1) ? bk : bv;
#pragma unroll
  for (int mi = 0; mi < 8; mi++)
#pragma unroll
    for (int ni = 0; ni < 4; ni++) {
      int col = (n0 & 1023) + wc * 64 + ni * 16 + lrow;
      float bval = bias[col];
      int row0 = m0 + wr * 128 + mi * 16 + quad * 4;
      if (seg == 0) {
#pragma unroll
        for (int r = 0; r < 4; r++)
          qout[(size_t)(row0 + r) * CH + col] =
              f2bf((acc[mi][ni][r] + bval) * 0.18033688011112042f);
      } else if (seg == 1) {
#pragma unroll
        for (int r = 0; r < 4; r++)
          kout[(size_t)(row0 + r) * CH + col] = f2bf(acc[mi][ni][r] + bval);
      } else {
        u16x4 pk;
#pragma unroll
        for (int r = 0; r < 4; r++) pk[r] = f2bf(acc[mi][ni][r] + bval);
        int b = row0 >> 10, t0 = row0 & 1023;
        int h = col >> 6, d = col & 63;
        *reinterpret_cast<u16x4*>(
            vt + (((size_t)(b * NH + h) * HD + d) << 10) + t0) = pk;
      }
    }
}

// ------------- 256^2 fused cross K/V GEMM: Bt = [cwkT|cwvT] (N=2048) -------------
__global__ __launch_bounds__(512, 2) void k_kv256(
    const u16* __restrict__ A, const u16* __restrict__ Bt,
    const float* __restrict__ bk, const float* __restrict__ bv,
    u16* __restrict__ kout, u16* __restrict__ vt) {
  __shared__ u16 AS[2 * 2 * 8192];
  __shared__ u16 BS[2 * 2 * 8192];
  int m0 = blockIdx.x * 256, n0 = blockIdx.y * 256;
  int tid = threadIdx.x;
  int wid = tid >> 6, lane = tid & 63;
  int wr = wid >> 2, wc = wid & 3;
  int lrow = lane & 15, quad = lane >> 4;
  f32x4 acc[8][4];
#pragma unroll
  for (int mi = 0; mi < 8; mi++)
#pragma unroll
    for (int ni = 0; ni < 4; ni++) acc[mi][ni] = {0.f, 0.f, 0.f, 0.f};
  gemm256_core(A, Bt, CH, m0, n0, tid, AS, BS, acc);
  int seg = n0 >> 10;
  const float* bias = (seg == 0) ? bk : bv;
#pragma unroll
  for (int mi = 0; mi < 8; mi++)
#pragma unroll
    for (int ni = 0; ni < 4; ni++) {
      int col = (n0 & 1023) + wc * 64 + ni * 16 + lrow;
      float bval = bias[col];
      int row0 = m0 + wr * 128 + mi * 16 + quad * 4;
      if (seg == 0) {
#pragma unroll
        for (int r = 0; r < 4; r++)
          kout[(size_t)(row0 + r) * CH + col] = f2bf(acc[mi][ni][r] + bval);
      } else {
        u16x4 pk;
#pragma unroll
        for (int r = 0; r < 4; r++) pk[r] = f2bf(acc[mi][ni][r] + bval);
        int b = row0 >> 10, t0 = row0 & 1023;
        int h = col >> 6, d = col & 63;
        *reinterpret_cast<u16x4*>(
            vt + (((size_t)(b * NH + h) * HD + d) << 10) + t0) = pk;
      }
    }
}

// ============ 256x128 8-phase GEMM core v3: 4x2 waves (64x64 tiles) ================
// Counter-verified in R9: fc2 98 -> 90.4 us, MfmaUtil 28 -> 30.7 (LDS-read traffic
// 160 -> 128 KB/K-tile). Same stage schedule / vmcnt ledger / barriers as v1.
template <int NB>
__device__ __forceinline__ void mfma_col2(const bf16x8 (&af)[4], const bf16x8 (&bfr)[2],
                                          f32x4 (&acc)[4][4]) {
#pragma unroll
  for (int mi = 0; mi < 4; mi++)
#pragma unroll
    for (int j = 0; j < 2; j++)
      acc[mi][NB + j] = __builtin_amdgcn_mfma_f32_16x16x32_bf16(af[mi], bfr[j],
                                                                acc[mi][NB + j], 0, 0, 0);
}

__device__ __forceinline__ void gemm128n_core(
    const u16* __restrict__ A, const u16* __restrict__ Bt, int K,
    int m0, int n0, int tid, u16* AS, u16* BS, f32x4 (&acc)[4][4]) {
  int wid = tid >> 6, lane = tid & 63;
  int wr = wid >> 1, wc = wid & 1;                   // 4M x 2N waves (64 x 64 each)
  int lrow = lane & 15, quad = lane >> 4;
  int sx = (quad ^ ((lrow >> 1) & 3)) * 8;
  int aRow = wr * 64 + lrow;
  int bRow = wc * 64 + lrow;
  int rA = tid >> 2;                                 // 0..127
  int qsw = (((tid & 3) ^ ((tid >> 3) & 3)) << 3);
  const u16* gA = A + (size_t)(m0 + rA) * K + qsw;
  const u16* gB = Bt + (size_t)(n0 + rA) * K + qsw;  // B tile: exactly 128 rows
  const size_t r128 = (size_t)128 * K;
  u16* dA = AS + tid * 8;
  u16* dB = BS + tid * 8;
  const int NT = K >> 6;                             // 16 (K=1024) or 64 (K=4096)

#define STGA(dd, hh, tt) do { const u16* s_ = gA + ((tt) * 64 + (hh) * 32); \
    u16* d_ = dA + ((dd) * 2 + (hh)) * 8192; \
    gload_lds16(s_, d_); gload_lds16(s_ + r128, d_ + 4096); } while (0)
#define STGB(dd, hh, tt) do { const u16* s_ = gB + ((tt) * 64 + (hh) * 32); \
    u16* d_ = dB + ((dd) * 2 + (hh)) * 4096; \
    gload_lds16(s_, d_); } while (0)
#define RD_A4(dd, kk) do { const u16* b_ = AS + ((dd) * 2 + (kk)) * 8192; \
    af[0] = ldbf8(&b_[(aRow) * 32 + sx]); \
    af[1] = ldbf8(&b_[(aRow + 16) * 32 + sx]); \
    af[2] = ldbf8(&b_[(aRow + 32) * 32 + sx]); \
    af[3] = ldbf8(&b_[(aRow + 48) * 32 + sx]); } while (0)
#define RD_B2(dd, kk, nh) do { const u16* b_ = BS + ((dd) * 2 + (kk)) * 4096; \
    int r_ = bRow + (nh) * 32; \
    bfr[0] = ldbf8(&b_[(r_) * 32 + sx]); \
    bfr[1] = ldbf8(&b_[(r_ + 16) * 32 + sx]); } while (0)
#define PHASE_TAIL(NBv) do { ASM_LGKM0(); __builtin_amdgcn_sched_barrier(0); \
    __builtin_amdgcn_s_setprio(1); mfma_col2<NBv>(af, bfr, acc); \
    __builtin_amdgcn_s_setprio(0); ASM_BAR(); } while (0)

  // prologue: 9 loads; t0k0 = oldest 3 (ledger identical to proven v1)
  STGA(0, 0, 0); STGB(0, 0, 0); STGA(0, 1, 0); STGB(0, 1, 0);
  STGA(1, 0, 1); STGB(1, 0, 1);
  ASM_VM6(); ASM_BAR();

  bf16x8 af[4], bfr[2];
  for (int t = 0; t < NT; ++t) {
    int d = t & 1;
    // p0: k0, A frags + B n-half0
    RD_A4(d, 0); RD_B2(d, 0, 0);
    if (t + 1 < NT) STGA(d ^ 1, 1, t + 1);
    PHASE_TAIL(0);
    // p1: k0, B n-half1 (A reused in registers)
    RD_B2(d, 0, 1);
    if (t + 1 < NT) STGB(d ^ 1, 1, t + 1);
    if (t == NT - 1) { ASM_VM0(); } else { ASM_VM6(); }
    PHASE_TAIL(2);
    // p2: k1, A frags + B n-half0
    RD_A4(d, 1); RD_B2(d, 1, 0);
    if (t + 2 < NT) STGA(d, 0, t + 2);
    PHASE_TAIL(0);
    // p3: k1, B n-half1
    RD_B2(d, 1, 1);
    if (t + 2 < NT) STGB(d, 0, t + 2);
    if (t < NT - 2) { ASM_VM6(); } else if (t == NT - 2) { ASM_VM3(); }
    PHASE_TAIL(2);
  }
#undef STGA
#undef STGB
#undef RD_A4
#undef RD_B2
#undef PHASE_TAIL
}

// ------------- 256x128 GEMM with fused epilogues -------------
// EPI 1: xb += mod[gate] * (acc+bias)
// EPI 3: out_bf = bf16((acc+bias) * 0.125*log2e)
// EPI 4: final fc2: dout[TBC-permuted] = xb + mod[gate]*(acc+bias)
template <int EPI>
__global__ __launch_bounds__(512, 2) void k_gemm128n(
    const u16* __restrict__ A, const u16* __restrict__ Bt,
    const float* __restrict__ bias, u16* __restrict__ out_bf,
    float* __restrict__ xb, float* __restrict__ dout,
    const float* __restrict__ mod, int gate_sel, int M, int N, int K) {
  __shared__ u16 AS[2 * 2 * 8192];
  __shared__ u16 BS[2 * 2 * 4096];
  int m0 = blockIdx.x * 256, n0 = blockIdx.y * 128;
  int tid = threadIdx.x;
  int wid = tid >> 6, lane = tid & 63;
  int wr = wid >> 1, wc = wid & 1;
  int lrow = lane & 15, quad = lane >> 4;
  f32x4 acc[4][4];
#pragma unroll
  for (int mi = 0; mi < 4; mi++)
#pragma unroll
    for (int ni = 0; ni < 4; ni++) acc[mi][ni] = {0.f, 0.f, 0.f, 0.f};
  gemm128n_core(A, Bt, K, m0, n0, tid, AS, BS, acc);
#pragma unroll
  for (int mi = 0; mi < 4; mi++)
#pragma unroll
    for (int ni = 0; ni < 4; ni++) {
      int col = n0 + wc * 64 + ni * 16 + lrow;
      float bval = bias[col];
#pragma unroll
      for (int r = 0; r < 4; r++) {
        int row = m0 + wr * 64 + mi * 16 + quad * 4 + r;
        float v = acc[mi][ni][r] + bval;
        if (EPI == 1) {
          int b = row >> 10;
          float g = mod[(size_t)b * (6 * CH) + (size_t)gate_sel * CH + col];
          xb[(size_t)row * N + col] += g * v;
        } else if (EPI == 3) {
          out_bf[(size_t)row * N + col] = f2bf(v * 0.18033688011112042f);
        } else {   // EPI 4
          int b = row >> 10, t = row & (T_SEQ - 1);
          float g = mod[(size_t)b * (6 * CH) + (size_t)gate_sel * CH + col];
          dout[((size_t)t * BATCH + b) * CH + col] =
              xb[(size_t)row * N + col] + g * v;
        }
      }
    }
}

// ------------- flash attention v5: software-pipelined K-tile loads ----------------
// Same math/layout as v4 (64 q-rows/wave, barrier-free, exp2 trick). Change: kt loop
// unrolled x2 with TWO named K-register sets (rule #20: no runtime-indexed regs);
// next tile's K/mask loads issue between P-store and P-read/PV, hiding K's L2
// latency (the only load consumed immediately after issue) under ~1000cy of PV.
// V stays single-buffered (consumed late; latency already hidden under QK+exp).
__device__ __forceinline__ void attn_kload(const u16* ksrc, const int* mrow, int kb,
                                           int lrow, bf16x8 (&kf)[8], float (&mb)[4]) {
#pragma unroll
  for (int sub = 0; sub < 4; sub++) {
    const u16* kp = ksrc + (size_t)(kb + sub * 16) * CH;
    kf[sub * 2] = ldbf8(kp);
    kf[sub * 2 + 1] = ldbf8(kp + 32);
    mb[sub] = mrow[kb + sub * 16 + lrow] ? -INFINITY : 0.0f;
  }
}

__device__ __forceinline__ void attn_body(
    int kb, const bf16x8 (&kf)[8], const float (&mb)[4],
    bool pre, const u16* ksrc, const int* mrow, int kbn,
    bf16x8 (&kfn)[8], float (&mbn)[4],
    const u16* vsrc, const bf16x8 (&aq)[4][2], const bf16x8& ones,
    int wid, int lrow, int quad, u16 (*P)[4][16][72], f32x4 (&o)[4][5]) {
  bf16x8 vf[8];
#pragma unroll
  for (int dc = 0; dc < 4; dc++) {
    const u16* vp = vsrc + (size_t)(dc * 16) * 1024 + kb;
    vf[dc * 2] = ldbf8(vp);
    vf[dc * 2 + 1] = ldbf8(vp + 32);
  }
  // QK + exp2 + P store, all 4 subtiles
#pragma unroll
  for (int st = 0; st < 4; st++) {
#pragma unroll
    for (int sub = 0; sub < 4; sub++) {
      f32x4 z = {0.f, 0.f, 0.f, 0.f};
      z = __builtin_amdgcn_mfma_f32_16x16x32_bf16(aq[st][0], kf[sub * 2], z, 0, 0, 0);
      z = __builtin_amdgcn_mfma_f32_16x16x32_bf16(aq[st][1], kf[sub * 2 + 1], z, 0, 0, 0);
      float mbv = mb[sub];
#pragma unroll
      for (int r = 0; r < 4; r++) {
        float p = exp2f(z[r] + mbv);   // exp2(-inf) = 0 handles masking
        P[wid][st][quad * 4 + r][sub * 16 + lrow] = f2bf_trunc(p);
      }
    }
  }
  // prefetch next K-tile while PV runs (hidden under MFMA)
  if (pre) attn_kload(ksrc, mrow, kbn, lrow, kfn, mbn);
  // P C-layout -> A-layout reads + PV (wave-private LDS, lgkmcnt-ordered)
#pragma unroll
  for (int st = 0; st < 4; st++) {
    bf16x8 pf0 = ldbf8(&P[wid][st][lrow][quad * 8]);
    bf16x8 pf1 = ldbf8(&P[wid][st][lrow][32 + quad * 8]);
#pragma unroll
    for (int dc = 0; dc < 4; dc++) {
      o[st][dc] = __builtin_amdgcn_mfma_f32_16x16x32_bf16(pf0, vf[dc * 2], o[st][dc], 0, 0, 0);
      o[st][dc] = __builtin_amdgcn_mfma_f32_16x16x32_bf16(pf1, vf[dc * 2 + 1], o[st][dc], 0, 0, 0);
    }
    o[st][4] = __builtin_amdgcn_mfma_f32_16x16x32_bf16(pf0, ones, o[st][4], 0, 0, 0);
    o[st][4] = __builtin_amdgcn_mfma_f32_16x16x32_bf16(pf1, ones, o[st][4], 0, 0, 0);
  }
}

__global__ __launch_bounds__(256, 2) void k_attn(
    const u16* __restrict__ Q, const u16* __restrict__ Kb,
    const u16* __restrict__ vt, const int* __restrict__ mask,
    u16* __restrict__ Y) {
  int qt = blockIdx.x, h = blockIdx.y, b = blockIdx.z;
  int tid = threadIdx.x, wid = tid >> 6, lane = tid & 63;
  int lrow = lane & 15, quad = lane >> 4;
  int qbase = qt * 256 + wid * 64;     // wave's 64 q-rows

  __shared__ u16 P[4][4][16][72];      // [wave][subtile][qrow][key] wave-private

  bf16x8 aq[4][2];
#pragma unroll
  for (int st = 0; st < 4; st++) {
    size_t qoff = ((size_t)(b * T_SEQ + qbase + st * 16 + lrow)) * CH + h * HD;
    aq[st][0] = ldbf8(Q + qoff + quad * 8);
    aq[st][1] = ldbf8(Q + qoff + 32 + quad * 8);
  }

  u16x8 uo;
#pragma unroll
  for (int j = 0; j < 8; j++) uo[j] = (lrow == 0) ? (u16)0x3F80 : (u16)0;
  bf16x8 ones = __builtin_bit_cast(bf16x8, uo);

  const int* mrow = mask + (size_t)b * T_SEQ;
  const u16* ksrc = Kb + ((size_t)(b * T_SEQ) + lrow) * CH + h * HD + quad * 8;
  const u16* vsrc = vt + (((size_t)(b * NH + h) * HD + lrow) << 10) + quad * 8;

  f32x4 o[4][5];
#pragma unroll
  for (int st = 0; st < 4; st++)
#pragma unroll
    for (int dc = 0; dc < 5; dc++) o[st][dc] = {0.f, 0.f, 0.f, 0.f};

  bf16x8 kfA[8], kfB[8];
  float mbA[4], mbB[4];
  attn_kload(ksrc, mrow, 0, lrow, kfA, mbA);

  for (int kt = 0; kt < 16; kt += 2) {
    // even tile: consume kfA, prefetch kfB for kt+1
    attn_body(kt * 64, kfA, mbA, true, ksrc, mrow, kt * 64 + 64, kfB, mbB,
              vsrc, aq, ones, wid, lrow, quad, P, o);
    // odd tile: consume kfB, prefetch kfA for kt+2 (if any)
    attn_body(kt * 64 + 64, kfB, mbB, (kt + 2 < 16), ksrc, mrow, kt * 64 + 128,
              kfA, mbA, vsrc, aq, ones, wid, lrow, quad, P, o);
  }

  // epilogue: l in col lrow==0 of o[st][4]; broadcast within 16-lane group
#pragma unroll
  for (int st = 0; st < 4; st++)
#pragma unroll
    for (int r = 0; r < 4; r++) {
      float l = __shfl(o[st][4][r], lane & 48);
      float linv = 1.0f / l;
      int qr = qbase + st * 16 + quad * 4 + r;
      size_t yo = ((size_t)(b * T_SEQ + qr)) * CH + h * HD;
#pragma unroll
      for (int dc = 0; dc < 4; dc++)
        Y[yo + dc * 16 + lrow] = f2bf(o[st][dc][r] * linv);
    }
}

extern "C" void kernel_launch(void* const* d_in, const int* in_sizes, int n_in,
                              void* d_out, int out_size, void* d_ws, size_t ws_size,
                              hipStream_t stream) {
  const float* x     = (const float*)d_in[0];
  const float* c     = (const float*)d_in[1];
  const int*   pmask = (const int*)d_in[2];
  const float* audio = (const float*)d_in[3];
  const int*   amask = (const int*)d_in[4];
  const float* w_ada = (const float*)d_in[5];
  const float* b_ada = (const float*)d_in[6];
  const float* wq = (const float*)d_in[7];  const float* bq = (const float*)d_in[8];
  const float* wk = (const float*)d_in[9];  const float* bk = (const float*)d_in[10];
  const float* wv = (const float*)d_in[11]; const float* bv = (const float*)d_in[12];
  const float* wo = (const float*)d_in[13]; const float* bo = (const float*)d_in[14];
  const float* cwq = (const float*)d_in[15]; const float* cbq = (const float*)d_in[16];
  const float* cwk = (const float*)d_in[17]; const float* cbk = (const float*)d_in[18];
  const float* cwv = (const float*)d_in[19]; const float* cbv = (const float*)d_in[20];
  const float* cwo = (const float*)d_in[21]; const float* cbo = (const float*)d_in[22];
  const float* w1 = (const float*)d_in[23]; const float* b1 = (const float*)d_in[24];
  const float* w2 = (const float*)d_in[25]; const float* b2 = (const float*)d_in[26];

  char* wsb = (char*)d_ws;
  size_t off = 0;
  auto alloc = [&](size_t bytes) {
    char* p = wsb + off;
    off += (bytes + 255) & ~(size_t)255;
    return p;
  };
  const size_t SQ = (size_t)CH * CH * 2;       // 2MB bf16 square weight
  u16* wqT  = (u16*)alloc(SQ);                 // wqT|wkT|wvT contiguous = QKV Bt
  u16* wkT  = (u16*)alloc(SQ);
  u16* wvT  = (u16*)alloc(SQ);
  u16* woT  = (u16*)alloc(SQ);
  u16* cwqT = (u16*)alloc(SQ);
  u16* cwkT = (u16*)alloc(SQ);                 // cwkT|cwvT contiguous = KV Bt
  u16* cwvT = (u16*)alloc(SQ);
  u16* cwoT = (u16*)alloc(SQ);
  u16* w1T  = (u16*)alloc((size_t)CH * MH * 2);
  u16* w2T  = (u16*)alloc((size_t)CH * MH * 2);
  float* mod = (float*)alloc((size_t)BATCH * 6 * CH * 4);
  float* xb  = (float*)alloc((size_t)BATCH * T_SEQ * CH * 4);
  u16* xm    = (u16*)alloc((size_t)BATCH * T_SEQ * CH * 2);
  u16* hbuf  = (u16*)alloc((size_t)BATCH * T_SEQ * MH * 2);
  u16* qbuf  = hbuf;
  u16* kbuf  = hbuf + (size_t)BATCH * T_SEQ * CH;
  u16* ybuf  = hbuf + (size_t)2 * BATCH * T_SEQ * CH;
  u16* vt    = hbuf + (size_t)3 * BATCH * T_SEQ * CH;
  u16* abuf  = (u16*)alloc((size_t)BATCH * TA_SEQ * CH * 2);
  (void)ws_size; (void)in_sizes; (void)n_in; (void)out_size;

  const int NE = T_SEQ * BATCH * CH;   // 8.39M elements
  dim3 tb32(32, 8);

  P8f src8; P8u dst8;
  src8.p[0] = wq;  dst8.p[0] = wqT;
  src8.p[1] = wk;  dst8.p[1] = wkT;
  src8.p[2] = wv;  dst8.p[2] = wvT;
  src8.p[3] = wo;  dst8.p[3] = woT;
  src8.p[4] = cwq; dst8.p[4] = cwqT;
  src8.p[5] = cwk; dst8.p[5] = cwkT;
  src8.p[6] = cwv; dst8.p[6] = cwvT;
  src8.p[7] = cwo; dst8.p[7] = cwoT;
  k_transpose8<<<dim3(CH / 32, CH / 32, 8), tb32, 0, stream>>>(src8, dst8);
  k_transpose_w<<<dim3(MH / 32, CH / 32), tb32, 0, stream>>>(w1, w1T, CH, MH);
  k_transpose_w<<<dim3(CH / 32, MH / 32), tb32, 0, stream>>>(w2, w2T, MH, CH);

  k_ada<<<dim3(6 * CH / 256, BATCH), 256, 0, stream>>>(c, w_ada, b_ada, mod);
  k_tbc_to_btc_bf16<<<NE / 256, 256, 0, stream>>>(audio, abuf);

  // ---- self-attention ----
  // fused: x(TBC) -> xb(BTC fp32) + LN+mod -> xm
  k_ln_mod<1><<<BATCH * T_SEQ, 256, 0, stream>>>(x, mod, xm, xb, 0, 1);
  k_qkv256<<<dim3(32, 12), 512, 0, stream>>>(xm, wqT, bq, bk, bv, qbuf, kbuf, vt);
  k_attn<<<dim3(T_SEQ / 256, NH, BATCH), 256, 0, stream>>>(qbuf, kbuf, vt, pmask, ybuf);
  k_gemm128n<1><<<dim3(32, 8), 512, 0, stream>>>(ybuf, woT, bo, nullptr, xb, nullptr, mod, 2, 8192, CH, CH);

  // ---- cross-attention (reuses msa shift/scale/gate) ----
  k_ln_mod<0><<<BATCH * T_SEQ, 256, 0, stream>>>(xb, mod, xm, nullptr, 0, 1);
  k_gemm128n<3><<<dim3(32, 8), 512, 0, stream>>>(xm, cwqT, cbq, qbuf, nullptr, nullptr, nullptr, 0, 8192, CH, CH);
  k_kv256<<<dim3(32, 8), 512, 0, stream>>>(abuf, cwkT, cbk, cbv, kbuf, vt);
  k_attn<<<dim3(T_SEQ / 256, NH, BATCH), 256, 0, stream>>>(qbuf, kbuf, vt, amask, ybuf);
  k_gemm128n<1><<<dim3(32, 8), 512, 0, stream>>>(ybuf, cwoT, cbo, nullptr, xb, nullptr, mod, 2, 8192, CH, CH);

  // ---- MLP ----
  k_ln_mod<0><<<BATCH * T_SEQ, 256, 0, stream>>>(xb, mod, xm, nullptr, 3, 4);
  k_gemm256<2><<<dim3(32, 16), 512, 0, stream>>>(xm, w1T, b1, hbuf, nullptr, nullptr, 0, 8192, MH, CH);
  // fc2 writes d_out directly in [T][B][C]
  k_gemm128n<4><<<dim3(32, 8), 512, 0, stream>>>(hbuf, w2T, b2, nullptr, xb, (float*)d_out, mod, 5, 8192, CH, MH);
}